// Round 10
// baseline (195.424 us; speedup 1.0000x reference)
//
#include <hip/hip_runtime.h>

typedef __bf16 bf16x8 __attribute__((ext_vector_type(8)));
typedef __bf16 bf16x4 __attribute__((ext_vector_type(4)));
typedef short short4v __attribute__((ext_vector_type(4)));
typedef float f32x4 __attribute__((ext_vector_type(4)));

__device__ __forceinline__ f32x4 mfma16(bf16x8 a, bf16x8 b, f32x4 c) {
  return __builtin_amdgcn_mfma_f32_16x16x32_bf16(a, b, c, 0, 0, 0);
}

// K=16 MFMA: C/D layout == B-operand layout -> S^T frags feed PV directly.
__device__ __forceinline__ f32x4 mfma16k16(bf16x4 a, bf16x4 b, f32x4 c) {
#if __has_builtin(__builtin_amdgcn_mfma_f32_16x16x16bf16_1k)
  short4v as = __builtin_bit_cast(short4v, a);
  short4v bs = __builtin_bit_cast(short4v, b);
  return __builtin_amdgcn_mfma_f32_16x16x16bf16_1k(as, bs, c, 0, 0, 0);
#else
  f32x4 d;
  asm volatile("v_mfma_f32_16x16x16_bf16 %0, %1, %2, %3"
               : "=v"(d)
               : "v"(a), "v"(b), "v"(c));
  return d;
#endif
}

__device__ __forceinline__ float fast_exp2(float x) {
  return __builtin_amdgcn_exp2f(x);  // v_exp_f32 (native exp2)
}

typedef const __attribute__((address_space(1))) void gvoid_t;
typedef __attribute__((address_space(3))) void svoid_t;
__device__ __forceinline__ void lds16(const __bf16* g, __bf16* l) {
  // async 16B/lane global->LDS; dest = wave-uniform base + lane*16
  __builtin_amdgcn_global_load_lds((gvoid_t*)g, (svoid_t*)l, 16, 0, 0);
}

// ---------------- fused fp32 -> bf16 convert of all inputs ----------------
__global__ __launch_bounds__(256) void prep(const float* __restrict__ hidden,
                                            const float* __restrict__ Wq,
                                            const float* __restrict__ Wk,
                                            const float* __restrict__ Wv,
                                            const float* __restrict__ Wo,
                                            __bf16* __restrict__ hb,
                                            __bf16* __restrict__ Wqkvb,
                                            __bf16* __restrict__ Wob) {
  int q = blockIdx.x * 256 + threadIdx.x;
  const float* src;
  __bf16* dst;
  if (q < 1048576) {
    src = hidden; dst = hb;
  } else if ((q -= 1048576) < 262144) {
    src = Wq; dst = Wqkvb;
  } else if ((q -= 262144) < 65536) {
    src = Wk; dst = Wqkvb + 1048576;
  } else if ((q -= 65536) < 65536) {
    src = Wv; dst = Wqkvb + 1310720;
  } else {
    q -= 65536;
    src = Wo; dst = Wob;
  }
  float4 v = *(const float4*)(src + (size_t)q * 4);
  bf16x4 o = { (__bf16)v.x, (__bf16)v.y, (__bf16)v.z, (__bf16)v.w };
  *(bf16x4*)(dst + (size_t)q * 4) = o;
}

// ------ NT GEMM, 128x128 tile, global_load_lds dbuf (QKV projection) ------
__global__ __launch_bounds__(256) void gemm_nt(const __bf16* __restrict__ A,
                                               const __bf16* __restrict__ B,
                                               __bf16* __restrict__ Cv, int N) {
  __shared__ __bf16 As[2][128][32];
  __shared__ __bf16 Bs[2][128][32];
  const int m0 = blockIdx.x * 128, n0 = blockIdx.y * 128;
  const int tid = threadIdx.x;
  const int wave = tid >> 6, lane = tid & 63, quad = lane >> 4, l16 = lane & 15;
  const int wr = wave >> 1, wc = wave & 1;
  const int srow = 32 * wave;  // wave stages rows srow..srow+31 (2 insts)
  const __bf16* Ag = A + (size_t)(m0 + srow + (lane >> 2)) * 1024 + (lane & 3) * 8;
  const __bf16* Bg = B + (size_t)(n0 + srow + (lane >> 2)) * 1024 + (lane & 3) * 8;
  f32x4 acc[4][4] = {};

  auto stage = [&](int buf, int k0) {
    lds16(Ag + k0, &As[buf][srow][0]);
    lds16(Ag + 16 * 1024 + k0, &As[buf][srow + 16][0]);
    lds16(Bg + k0, &Bs[buf][srow][0]);
    lds16(Bg + 16 * 1024 + k0, &Bs[buf][srow + 16][0]);
  };
  stage(0, 0);
  __syncthreads();
  int buf = 0;
  for (int k0 = 0; k0 < 1024; k0 += 32) {
    if (k0 + 32 < 1024) stage(buf ^ 1, k0 + 32);
    bf16x8 af[4], bfr[4];
#pragma unroll
    for (int i = 0; i < 4; i++)
      af[i] = *(bf16x8*)&As[buf][64 * wr + 16 * i + l16][quad * 8];
#pragma unroll
    for (int j = 0; j < 4; j++)
      bfr[j] = *(bf16x8*)&Bs[buf][64 * wc + 16 * j + l16][quad * 8];
#pragma unroll
    for (int i = 0; i < 4; i++)
#pragma unroll
      for (int j = 0; j < 4; j++) acc[i][j] = mfma16(af[i], bfr[j], acc[i][j]);
    __syncthreads();
    buf ^= 1;
  }
#pragma unroll
  for (int i = 0; i < 4; i++)
#pragma unroll
    for (int j = 0; j < 4; j++)
#pragma unroll
      for (int r = 0; r < 4; r++) {
        int row = m0 + 64 * wr + 16 * i + quad * 4 + r;
        int col = n0 + 64 * wc + 16 * j + l16;
        Cv[(size_t)row * N + col] = (__bf16)acc[i][j][r];
      }
}

// ------ Wo GEMM with fused split-K combine in the A-staging ------
// A[row][k] = (f32(Op0[row][k]) + f32(Op1[row][k])) / (rs_z0 + rs_z1), formed
// in registers and ds_write'd into the same [128][32] LDS layout. B via lds16.
__global__ __launch_bounds__(256) void gemm_wo(const __bf16* __restrict__ Op0,
                                               const __bf16* __restrict__ Op1,
                                               const float* __restrict__ rspart,
                                               const __bf16* __restrict__ B,
                                               float* __restrict__ C) {
  __shared__ __bf16 As[2][128][32];
  __shared__ __bf16 Bs[2][128][32];
  const int m0 = blockIdx.x * 128, n0 = blockIdx.y * 128;
  const int tid = threadIdx.x;
  const int wave = tid >> 6, lane = tid & 63, quad = lane >> 4, l16 = lane & 15;
  const int wr = wave >> 1, wc = wave & 1;
  const int srow = 32 * wave;
  const int r_in = srow + (lane >> 2), c_in = (lane & 3) * 8;
  const int grow0 = m0 + r_in, grow1 = grow0 + 16;
  const int b0 = grow0 >> 11, q0 = grow0 & 2047;
  const int b1 = grow1 >> 11, q1 = grow1 & 2047;
  const __bf16* Bg = B + (size_t)(n0 + r_in) * 1024 + c_in;
  f32x4 acc[4][4] = {};

  auto loadA = [&](int k0, bf16x8& a00, bf16x8& a01, bf16x8& a10, bf16x8& a11,
                   float& i0, float& i1) {
    const int h = k0 >> 5;  // c_in in {0,8,16,24}: whole stage is one head
    a00 = *(const bf16x8*)(Op0 + (size_t)grow0 * 1024 + k0 + c_in);
    a01 = *(const bf16x8*)(Op1 + (size_t)grow0 * 1024 + k0 + c_in);
    a10 = *(const bf16x8*)(Op0 + (size_t)grow1 * 1024 + k0 + c_in);
    a11 = *(const bf16x8*)(Op1 + (size_t)grow1 * 1024 + k0 + c_in);
    i0 = 1.0f / (rspart[((size_t)b0 * 32 + h) * 2048 + q0] +
                 rspart[((size_t)(2 + b0) * 32 + h) * 2048 + q0]);
    i1 = 1.0f / (rspart[((size_t)b1 * 32 + h) * 2048 + q1] +
                 rspart[((size_t)(2 + b1) * 32 + h) * 2048 + q1]);
  };
  auto writeA = [&](int buf, bf16x8 a00, bf16x8 a01, bf16x8 a10, bf16x8 a11,
                    float i0, float i1) {
    bf16x8 w0, w1;
#pragma unroll
    for (int e = 0; e < 8; e++) {
      w0[e] = (__bf16)(((float)a00[e] + (float)a01[e]) * i0);
      w1[e] = (__bf16)(((float)a10[e] + (float)a11[e]) * i1);
    }
    *(bf16x8*)&As[buf][r_in][c_in] = w0;
    *(bf16x8*)&As[buf][r_in + 16][c_in] = w1;
  };

  {  // prologue: tile 0
    bf16x8 a00, a01, a10, a11;
    float i0, i1;
    loadA(0, a00, a01, a10, a11, i0, i1);
    lds16(Bg, &Bs[0][srow][0]);
    lds16(Bg + 16 * 1024, &Bs[0][srow + 16][0]);
    writeA(0, a00, a01, a10, a11, i0, i1);
  }
  __syncthreads();
  int buf = 0;
  for (int k0 = 0; k0 < 1024; k0 += 32) {
    const bool more = (k0 + 32) < 1024;
    bf16x8 a00, a01, a10, a11;
    float i0, i1;
    if (more) {  // issue next tile's loads before compute
      loadA(k0 + 32, a00, a01, a10, a11, i0, i1);
      lds16(Bg + k0 + 32, &Bs[buf ^ 1][srow][0]);
      lds16(Bg + 16 * 1024 + k0 + 32, &Bs[buf ^ 1][srow + 16][0]);
    }
    bf16x8 af[4], bfr[4];
#pragma unroll
    for (int i = 0; i < 4; i++)
      af[i] = *(bf16x8*)&As[buf][64 * wr + 16 * i + l16][quad * 8];
#pragma unroll
    for (int j = 0; j < 4; j++)
      bfr[j] = *(bf16x8*)&Bs[buf][64 * wc + 16 * j + l16][quad * 8];
#pragma unroll
    for (int i = 0; i < 4; i++)
#pragma unroll
      for (int j = 0; j < 4; j++) acc[i][j] = mfma16(af[i], bfr[j], acc[i][j]);
    if (more) writeA(buf ^ 1, a00, a01, a10, a11, i0, i1);
    __syncthreads();
    buf ^= 1;
  }
#pragma unroll
  for (int i = 0; i < 4; i++)
#pragma unroll
    for (int j = 0; j < 4; j++)
#pragma unroll
      for (int r = 0; r < 4; r++) {
        int row = m0 + 64 * wr + 16 * i + quad * 4 + r;
        int col = n0 + 64 * wc + 16 * j + l16;
        C[(size_t)row * 1024 + col] = acc[i][j][r];
      }
}

// --------- fused RoPE (in-place on QKV) + V transpose + mask bias ----------
__global__ __launch_bounds__(256) void ropevt(__bf16* __restrict__ QKV,
                                              __bf16* __restrict__ VT,
                                              const int* __restrict__ amask,
                                              float* __restrict__ maskb) {
  int idx = blockIdx.x * 256 + threadIdx.x;
  if (idx < 2621440) {
    __bf16* base;
    int m, i;
    if (idx < 2097152) {
      m = idx >> 9;
      int h = (idx >> 4) & 31;
      i = idx & 15;
      base = QKV + (size_t)m * 1536 + h * 32;
    } else {
      int j = idx - 2097152;
      m = j >> 7;
      int h = (j >> 4) & 7;
      i = j & 15;
      base = QKV + (size_t)m * 1536 + 1024 + h * 32;
    }
    int s = m & 2047;
    float inv = __expf(-(float)i * 0.5756462732485114f);  // 10000^(-i/16)
    float ang = (float)s * inv;
    float sn, cs;
    __sincosf(ang, &sn, &cs);
    float x0 = (float)base[i];
    float x1 = (float)base[i + 16];
    base[i] = (__bf16)(x0 * cs - x1 * sn);
    base[i + 16] = (__bf16)(x1 * cs + x0 * sn);
  } else {
    int j = idx - 2621440;
    if (j < 4096) maskb[j] = amask[j] ? -16.0f : -1.5e9f;  // static max folded in
    int s4 = j & 511;
    int d = (j >> 9) & 31;
    int hb_ = j >> 14;
    int s = s4 * 4;
    int b_ = hb_ >> 3, hkv_ = hb_ & 7;
    const __bf16* src = QKV + (size_t)(b_ * 2048 + s) * 1536 + 1280 + hkv_ * 32 + d;
    bf16x4 ov = { src[0], src[1536], src[3072], src[4608] };
    *(bf16x4*)&VT[((size_t)hb_ * 32 + d) * 2048 + s] = ov;
  }
}

// ------- Flash attention, split-K partials (static max => associative) ------
// Block (xp, z): strips {xp, 15-xp}; z=0 first half of each strip's tiles,
// z=1 second half -> uniform 17 tiles/block. Emits bf16 O-partials + f32 rs.
__global__ __launch_bounds__(256, 4) void attn(const __bf16* __restrict__ QKV,
                                               const __bf16* __restrict__ VT,
                                               const float* __restrict__ maskb,
                                               __bf16* __restrict__ Opart,
                                               float* __restrict__ rspart) {
  __shared__ __bf16 Ks[2][64][40];
  __shared__ __bf16 Vs[2][32][72];
  const int tid = threadIdx.x;
  const int wave = tid >> 6, lane = tid & 63;
  const int quad = lane >> 4, l16 = lane & 15;
  const int b = blockIdx.z, h = blockIdx.y, hkv = h >> 2;
  const int xp = blockIdx.x >> 1, z = blockIdx.x & 1;
  const float SC2 = 0.25503472f;  // (1/sqrt(32)) * log2(e)

  const int sk_key = tid >> 2, sk_ch = (tid & 3) * 8;
  const int sv_d = tid >> 3, sv_seg = (tid & 7) * 8;
  const __bf16* ksrc = QKV + (size_t)(b * 2048 + sk_key) * 1536 + 1024 + hkv * 32 + sk_ch;
  const __bf16* vsrc = VT + ((size_t)(b * 8 + hkv) * 32 + sv_d) * 2048 + sv_seg;
  const float* mrow = maskb + b * 2048;

  for (int sp = 0; sp < 2; sp++) {
    const int strip = sp ? 15 - xp : xp;
    const int t_begin = z ? (strip + 1) : 0;
    const int t_end = z ? (2 * strip + 2) : (strip + 1);
    const int qw = strip * 128 + wave * 32;
    const int q_row0 = qw + l16, q_row1 = qw + 16 + l16;
    const __bf16* qbase = QKV + (size_t)(b * 2048 + qw + l16) * 1536 + h * 32 + quad * 8;
    bf16x8 qf0 = *(const bf16x8*)qbase;
    bf16x8 qf1 = *(const bf16x8*)(qbase + 16 * 1536);

    {  // stage tile t_begin into buffer 0
      uint4 kr = *(const uint4*)(ksrc + (size_t)t_begin * 64 * 1536);
      uint4 vr = *(const uint4*)(vsrc + (size_t)t_begin * 64);
      *(uint4*)&Ks[0][sk_key][sk_ch] = kr;
      *(uint4*)&Vs[0][sv_d][sv_seg] = vr;
    }
    __syncthreads();

    f32x4 o00 = {}, o01 = {}, o10 = {}, o11 = {};
    float rs0 = 0.f, rs1 = 0.f;
    int buf = 0;

    for (int t = t_begin; t < t_end; t++) {
      const int kv0 = t << 6;
      const bool more = (t + 1 < t_end);
      uint4 kr, vr;
      if (more) {
        kr = *(const uint4*)(ksrc + (size_t)(t + 1) * 64 * 1536);
        vr = *(const uint4*)(vsrc + (size_t)(t + 1) * 64);
      }
      if (kv0 <= qw + 31) {  // wave-uniform: any visible key?
        bf16x8 kf[4];
#pragma unroll
        for (int kt = 0; kt < 4; kt++)
          kf[kt] = *(bf16x8*)&Ks[buf][16 * kt + l16][quad * 8];
        f32x4 s0[4], s1[4];
#pragma unroll
        for (int kt = 0; kt < 4; kt++) {
          f32x4 zz = {};
          s0[kt] = mfma16(kf[kt], qf0, zz);
          s1[kt] = mfma16(kf[kt], qf1, zz);
        }
        // ---- static-max softmax -> packed B-operands (registers only) ----
        bf16x4 pb0[4], pb1[4];
        if (kv0 + 63 <= qw) {  // full tile
#pragma unroll
          for (int kt = 0; kt < 4; kt++) {
            const int kb = kv0 + 16 * kt + 4 * quad;
            float4 mb = *(const float4*)(mrow + kb);
#pragma unroll
            for (int r = 0; r < 4; r++) {
              float e0 = fast_exp2(fmaf(s0[kt][r], SC2, (&mb.x)[r]));
              float e1 = fast_exp2(fmaf(s1[kt][r], SC2, (&mb.x)[r]));
              rs0 += e0;
              rs1 += e1;
              pb0[kt][r] = (__bf16)e0;
              pb1[kt][r] = (__bf16)e1;
            }
          }
        } else {  // diagonal tile
#pragma unroll
          for (int kt = 0; kt < 4; kt++) {
            const int kb = kv0 + 16 * kt + 4 * quad;
            float4 mb = *(const float4*)(mrow + kb);
#pragma unroll
            for (int r = 0; r < 4; r++) {
              const int key = kb + r;
              float e0 = fast_exp2(fmaf(s0[kt][r], SC2, (&mb.x)[r]));
              float e1 = fast_exp2(fmaf(s1[kt][r], SC2, (&mb.x)[r]));
              e0 = (key <= q_row0) ? e0 : 0.f;
              e1 = (key <= q_row1) ? e1 : 0.f;
              rs0 += e0;
              rs1 += e1;
              pb0[kt][r] = (__bf16)e0;
              pb1[kt][r] = (__bf16)e1;
            }
          }
        }
        // ---- PV via K=16 MFMA: A = V^T frags (8B LDS reads), B = pb regs ---
#pragma unroll
        for (int kt = 0; kt < 4; kt++) {
          bf16x4 v0 = *(bf16x4*)&Vs[buf][l16][16 * kt + 4 * quad];
          bf16x4 v1 = *(bf16x4*)&Vs[buf][16 + l16][16 * kt + 4 * quad];
          o00 = mfma16k16(v0, pb0[kt], o00);
          o01 = mfma16k16(v1, pb0[kt], o01);
          o10 = mfma16k16(v0, pb1[kt], o10);
          o11 = mfma16k16(v1, pb1[kt], o11);
        }
      }
      if (more) {
        *(uint4*)&Ks[buf ^ 1][sk_key][sk_ch] = kr;
        *(uint4*)&Vs[buf ^ 1][sv_d][sv_seg] = vr;
      }
      __syncthreads();
      buf ^= 1;
    }
    // ---- partial epilogue: reduce rs; store bf16 unnormalized O + f32 rs ----
    rs0 += __shfl_xor(rs0, 16);
    rs0 += __shfl_xor(rs0, 32);
    rs1 += __shfl_xor(rs1, 16);
    rs1 += __shfl_xor(rs1, 32);
    __bf16* Op = Opart + (size_t)z * 4096 * 1024;
    size_t row0 = (size_t)(b * 2048 + q_row0);
    size_t row1 = (size_t)(b * 2048 + q_row1);
    bf16x4 w00 = { (__bf16)o00[0], (__bf16)o00[1], (__bf16)o00[2], (__bf16)o00[3] };
    bf16x4 w01 = { (__bf16)o01[0], (__bf16)o01[1], (__bf16)o01[2], (__bf16)o01[3] };
    bf16x4 w10 = { (__bf16)o10[0], (__bf16)o10[1], (__bf16)o10[2], (__bf16)o10[3] };
    bf16x4 w11 = { (__bf16)o11[0], (__bf16)o11[1], (__bf16)o11[2], (__bf16)o11[3] };
    *(bf16x4*)&Op[row0 * 1024 + h * 32 + quad * 4] = w00;
    *(bf16x4*)&Op[row0 * 1024 + h * 32 + 16 + quad * 4] = w01;
    *(bf16x4*)&Op[row1 * 1024 + h * 32 + quad * 4] = w10;
    *(bf16x4*)&Op[row1 * 1024 + h * 32 + 16 + quad * 4] = w11;
    if (quad == 0) {
      size_t ri = ((size_t)(z * 2 + b) * 32 + h) * 2048;
      rspart[ri + q_row0] = rs0;
      rspart[ri + q_row1] = rs1;
    }
  }
}

extern "C" void kernel_launch(void* const* d_in, const int* in_sizes, int n_in,
                              void* d_out, int out_size, void* d_ws, size_t ws_size,
                              hipStream_t stream) {
  const float* hidden = (const float*)d_in[0];
  const int* amask = (const int*)d_in[1];
  const float* Wq = (const float*)d_in[2];
  const float* Wk = (const float*)d_in[3];
  const float* Wv = (const float*)d_in[4];
  const float* Wo = (const float*)d_in[5];
  float* out = (float*)d_out;

  char* p = (char*)d_ws;
  auto carve = [&](size_t elems) {
    __bf16* r = (__bf16*)p;
    p += ((elems * 2 + 255) / 256) * 256;
    return r;
  };
  __bf16* hb = carve(4096ull * 1024);
  __bf16* Wqkvb = carve(1536ull * 1024);
  __bf16* Wob = carve(1024ull * 1024);
  __bf16* QKV = carve(4096ull * 1536);
  __bf16* VT = carve(4096ull * 256);
  float* maskb = (float*)carve(8192);               // 4096 f32
  __bf16* Opart = carve(2ull * 4096 * 1024);        // 2 x 8 MB bf16 partials
  float* rspart = (float*)carve(2ull * 2 * 32 * 2048 * 2);

  prep<<<6656, 256, 0, stream>>>(hidden, Wq, Wk, Wv, Wo, hb, Wqkvb, Wob);

  gemm_nt<<<dim3(32, 12), 256, 0, stream>>>(hb, Wqkvb, QKV, 1536);

  ropevt<<<11264, 256, 0, stream>>>(QKV, VT, amask, maskb);

  attn<<<dim3(16, 32, 2), 256, 0, stream>>>(QKV, VT, maskb, Opart, rspart);

  gemm_wo<<<dim3(32, 8), 256, 0, stream>>>(Opart, Opart + 4096ull * 1024,
                                           rspart, Wob, out);
}